// Round 5
// baseline (1104.425 us; speedup 1.0000x reference)
//
#include <hip/hip_runtime.h>
#include <hip/hip_bf16.h>
#include <math.h>

typedef __hip_bfloat16 bf16;
typedef unsigned short ushort_t;
typedef unsigned int uint_t;
typedef short v8s __attribute__((ext_vector_type(8)));
typedef float v4f __attribute__((ext_vector_type(4)));

#define NVTOK 9072
#define BATCH 8
#define LT 32
#define DMODEL 256
#define NHEAD 8
#define DHEAD 32
#define MVIS (BATCH*NVTOK)   /* 72576 */
#define MTEXT (BATCH*LT)     /* 256 */
#define VISSZ 18579456ull    /* MVIS*256 elements */
#define AST 40               /* padded LDS stride (ushorts) */

__device__ __forceinline__ float bf2f(ushort_t u){ return __uint_as_float(((uint_t)u)<<16); }
__device__ __forceinline__ ushort_t f2bfbits(float f){
  __hip_bfloat16 h = __float2bfloat16(f);
  union { __hip_bfloat16 h; ushort_t u; } c; c.h = h; return c.u;
}
// mode: 0 = buffers hold bf16, 1 = buffers hold fp32
__device__ __forceinline__ float ldin(const void* p, size_t i, int mode){
  return mode ? ((const float*)p)[i] : bf2f(((const ushort_t*)p)[i]);
}
__device__ __forceinline__ void stout(void* p, size_t i, int mode, float v){
  if (mode) ((float*)p)[i] = v; else ((ushort_t*)p)[i] = f2bfbits(v);
}

// ---------------------------------------------------------------------------
// D0: dtype detector (unchanged)
// ---------------------------------------------------------------------------
__global__ void k_detect(const uint_t* __restrict__ buf, int n_avail, int* __restrict__ flag){
  __shared__ int zc, bc;
  if (threadIdx.x==0){ zc=0; bc=0; }
  __syncthreads();
  int stride = n_avail/2048; if (stride < 1) stride = 1;
  int nz=0, nb=0;
  for (int i=threadIdx.x; i<2048; i+=256){
    long long idx = (long long)i*stride;
    if (idx >= n_avail) break;
    uint_t d = buf[idx];
    uint_t lo = d & 0xFFFFu;
    int e = (int)((lo >> 7) & 0xFF);
    if (lo == 0) nz++;
    else if (e >= 90 && e <= 160) nb++;
  }
  atomicAdd(&zc, nz); atomicAdd(&bc, nb);
  __syncthreads();
  if (threadIdx.x==0){
    int mode;
    if (zc > 1024) mode = 1;
    else if (bc > 1228) mode = 0;
    else mode = 1;
    *flag = mode;
  }
}

// ---------------------------------------------------------------------------
// W-transpose (unchanged)
// ---------------------------------------------------------------------------
__global__ __launch_bounds__(256) void k_transpose(
    const void* W, ushort_t* __restrict__ Wt, int K, int N,
    const int* __restrict__ mf)
{
  const int mode = *mf;
  __shared__ float tile[32][33];
  const int k0 = blockIdx.x*32, n0 = blockIdx.y*32;
  const int c = threadIdx.x & 31, r8 = threadIdx.x >> 5;
  #pragma unroll
  for (int i=0;i<4;i++){
    const int kk = r8 + i*8;
    tile[kk][c] = ldin(W, (size_t)(k0+kk)*N + n0 + c, mode);
  }
  __syncthreads();
  #pragma unroll
  for (int i=0;i<4;i++){
    const int nn = r8 + i*8;
    Wt[(size_t)(n0+nn)*K + k0 + c] = f2bfbits(tile[c][nn]);
  }
}

// ---------------------------------------------------------------------------
// T1: text prep (unchanged)
// ---------------------------------------------------------------------------
__global__ __launch_bounds__(256) void k_text_prep(
    const void* text,
    const void* ref_w, const void* ref_b,
    const void* off_w, const void* off_b,
    const void* aw_w,  const void* aw_b,
    float* __restrict__ loc_out, float* __restrict__ aw_out,
    const int* __restrict__ mf)
{
  const int mode = *mf;
  const int r = blockIdx.x;
  const int t = threadIdx.x;
  __shared__ float x[256];
  __shared__ float refv[6];
  __shared__ float offv[192];
  __shared__ float logit[96];
  x[t] = ldin(text, (size_t)r*256 + t, mode);
  __syncthreads();
  if (t < 192) {
    float s = 0.f;
    for (int k=0;k<256;k++) s += x[k]*ldin(off_w, (size_t)k*192+t, mode);
    offv[t] = s + ldin(off_b, t, mode);
  } else if (t < 198) {
    int j = t-192;
    float s = 0.f;
    for (int k=0;k<256;k++) s += x[k]*ldin(ref_w, (size_t)k*6+j, mode);
    s += ldin(ref_b, j, mode);
    refv[j] = 1.f/(1.f+expf(-s));
  }
  if (t < 96) {
    float s = 0.f;
    for (int k=0;k<256;k++) s += x[k]*ldin(aw_w, (size_t)k*96+t, mode);
    logit[t] = s + ldin(aw_b, t, mode);
  }
  __syncthreads();
  if (t < 8) {
    float mx = -1e30f;
    for (int j=0;j<12;j++) mx = fmaxf(mx, logit[t*12+j]);
    float e[12]; float den = 0.f;
    for (int j=0;j<12;j++){ e[j] = expf(logit[t*12+j]-mx); den += e[j]; }
    float inv = 1.f/den;
    for (int j=0;j<12;j++) aw_out[(size_t)r*96 + t*12 + j] = e[j]*inv;
  }
  if (t < 192) {
    int rem = t % 24;
    int l = rem >> 3;
    int c = t & 1;
    const float normW[3] = {96.f,48.f,24.f};
    const float normH[3] = {72.f,36.f,18.f};
    float nrm = (c==0) ? normW[l] : normH[l];
    loc_out[(size_t)r*192 + t] = refv[l*2+c] + offv[t]/nrm;
  }
}

// ---------------------------------------------------------------------------
// T2: deformable sampling, lazy vproj (unchanged)
// ---------------------------------------------------------------------------
__global__ __launch_bounds__(64) void k_deform(
    const void* vis_value, const char* __restrict__ vmask,
    const void* vproj_w, const void* vproj_b,
    const float* __restrict__ loc, const float* __restrict__ aw,
    float* __restrict__ ctx_out, const int* __restrict__ mf)
{
  const int mode = *mf;
  const int blk = blockIdx.x;      // r*8 + h
  const int r = blk >> 3;
  const int h = blk & 7;
  const int b = r >> 5;
  const int t = threadIdx.x;
  const int Hs[3] = {72,36,18};
  const int Wsz[3] = {96,48,24};
  const int stl[3] = {0,6912,8640};
  float s0=0.f,s1=0.f,s2=0.f,s3=0.f, wsum=0.f;
  for (int l=0;l<3;l++){
    for (int p=0;p<4;p++){
      const int sIdx = blk*12 + l*4 + p;
      const float a  = aw[sIdx];
      const float X = loc[sIdx*2+0]*(float)Wsz[l] - 0.5f;
      const float Y = loc[sIdx*2+1]*(float)Hs[l] - 0.5f;
      const float x0f = floorf(X), y0f = floorf(Y);
      const int x0 = (int)x0f, y0 = (int)y0f;
      const float wx = X-x0f, wy = Y-y0f;
      const float cw[4] = {(1.f-wx)*(1.f-wy), wx*(1.f-wy), (1.f-wx)*wy, wx*wy};
      const int cx[4] = {x0,x0+1,x0,x0+1};
      const int cy[4] = {y0,y0,y0+1,y0+1};
      for (int c=0;c<4;c++){
        if (cx[c]>=0 && cx[c]<Wsz[l] && cy[c]>=0 && cy[c]<Hs[l]){
          const size_t pos = (size_t)b*NVTOK + stl[l] + cy[c]*Wsz[l] + cx[c];
          if (vmask[pos]) continue;
          const float w = a*cw[c];
          wsum += w;
          const size_t base = pos*256 + t*4;
          s0 += w*ldin(vis_value, base+0, mode);
          s1 += w*ldin(vis_value, base+1, mode);
          s2 += w*ldin(vis_value, base+2, mode);
          s3 += w*ldin(vis_value, base+3, mode);
        }
      }
    }
  }
  __shared__ float sh[256];
  sh[t*4+0]=s0; sh[t*4+1]=s1; sh[t*4+2]=s2; sh[t*4+3]=s3;
  __syncthreads();
  if (t < 32) {
    const int col = h*32 + t;
    float acc = wsum * ldin(vproj_b, col, mode);
    for (int k=0;k<256;k++) acc += sh[k]*ldin(vproj_w, (size_t)k*256+col, mode);
    ctx_out[(size_t)r*256 + col] = acc;
  }
}

__device__ __forceinline__ float block_sum(float v, float* red){
  float sm = v;
  #pragma unroll
  for (int o=32;o>0;o>>=1) sm += __shfl_down(sm,o);
  const int t = threadIdx.x;
  __syncthreads();
  if ((t&63)==0) red[t>>6] = sm;
  __syncthreads();
  return red[0]+red[1]+red[2]+red[3];
}

// ---------------------------------------------------------------------------
// MFMA GEMM (text side, unchanged — tiny M)
// ---------------------------------------------------------------------------
__global__ __launch_bounds__(256) void k_mgemm(
    const void* A, size_t a_off, int a_kind,
    const ushort_t* __restrict__ Wt, const void* bias, float* __restrict__ C,
    int N, int K, int relu, const int* __restrict__ mf)
{
  const int mode = *mf;
  const int split = (a_kind==1) || (mode==1);
  __shared__ ushort_t Ah[128*32];
  __shared__ ushort_t Al[128*32];
  __shared__ ushort_t Bt[128*32];
  const int tid = threadIdx.x;
  const int gm0 = blockIdx.x*128, gn0 = blockIdx.y*128;
  const int wv = tid>>6, lane = tid&63;
  const int mh = (wv&1)*64, nh = (wv>>1)*64;
  const int r16 = lane&15, q8 = (lane>>4)*8;
  const int srow = tid>>1, sseg = (tid&1)*16;
  v4f acc[4][4];
  #pragma unroll
  for (int i=0;i<4;i++)
    #pragma unroll
    for (int j=0;j<4;j++) acc[i][j] = (v4f){0.f,0.f,0.f,0.f};

  for (int k0=0; k0<K; k0+=32){
    if (k0) __syncthreads();
    {
      const ushort_t* src = Wt + (size_t)(gn0+srow)*K + k0 + sseg;
      ((uint4*)&Bt[srow*32+sseg])[0]   = ((const uint4*)src)[0];
      ((uint4*)&Bt[srow*32+sseg+8])[0] = ((const uint4*)src)[1];
    }
    if (!split){
      const ushort_t* src = (const ushort_t*)A + a_off + (size_t)(gm0+srow)*K + k0 + sseg;
      ((uint4*)&Ah[srow*32+sseg])[0]   = ((const uint4*)src)[0];
      ((uint4*)&Ah[srow*32+sseg+8])[0] = ((const uint4*)src)[1];
    } else {
      const float* src = (const float*)A + a_off + (size_t)(gm0+srow)*K + k0 + sseg;
      #pragma unroll
      for (int v=0;v<4;v++){
        float4 f = ((const float4*)src)[v];
        float xs[4] = {f.x, f.y, f.z, f.w};
        #pragma unroll
        for (int e=0;e<4;e++){
          const int idx = srow*32 + sseg + v*4 + e;
          const ushort_t h = f2bfbits(xs[e]);
          Ah[idx] = h;
          Al[idx] = f2bfbits(xs[e] - bf2f(h));
        }
      }
    }
    __syncthreads();
    v8s af[4], bfr[4], al[4];
    #pragma unroll
    for (int mt=0;mt<4;mt++){
      af[mt] = *(const v8s*)&Ah[(mh + mt*16 + r16)*32 + q8];
      if (split) al[mt] = *(const v8s*)&Al[(mh + mt*16 + r16)*32 + q8];
    }
    #pragma unroll
    for (int nt=0;nt<4;nt++)
      bfr[nt] = *(const v8s*)&Bt[(nh + nt*16 + r16)*32 + q8];
    #pragma unroll
    for (int mt=0;mt<4;mt++){
      #pragma unroll
      for (int nt=0;nt<4;nt++){
        acc[mt][nt] = __builtin_amdgcn_mfma_f32_16x16x32_bf16(af[mt], bfr[nt], acc[mt][nt], 0, 0, 0);
        if (split)
          acc[mt][nt] = __builtin_amdgcn_mfma_f32_16x16x32_bf16(al[mt], bfr[nt], acc[mt][nt], 0, 0, 0);
      }
    }
  }
  const int rq = (lane>>4)*4;
  float bv[4];
  #pragma unroll
  for (int nt=0;nt<4;nt++) bv[nt] = ldin(bias, gn0 + nh + nt*16 + r16, mode);
  #pragma unroll
  for (int mt=0;mt<4;mt++){
    #pragma unroll
    for (int r=0;r<4;r++){
      const size_t ro = (size_t)(gm0 + mh + mt*16 + rq + r)*N + gn0 + nh + r16;
      #pragma unroll
      for (int nt=0;nt<4;nt++){
        float v = acc[mt][nt][r] + bv[nt];
        if (relu) v = fmaxf(v, 0.f);
        C[ro + nt*16] = v;
      }
    }
  }
}

// ---------------------------------------------------------------------------
// V2 MFMA GEMM (vis side). mode0: activations are bf16-single, 1 MFMA pass
// (exact bf16 inputs; LN/attn outputs rounded to bf16 — err ~1e-3 vs 0.109
// budget). mode1: full hi/lo pair path (unchanged numerics).
//   a_kind=0: raw input. a_kind=2: activation (hi ptr = A, lo ptr = Alo_p).
//   output: Cf!=null -> fp32; else pair (Chi always, Clo only in mode1).
// LDS stride AST=40 (conflict-reduced). XCD-bijective swizzle, n-fastest.
// ---------------------------------------------------------------------------
__global__ __launch_bounds__(256) void k_mgemm2(
    const void* A, size_t a_off, int a_kind,
    const ushort_t* __restrict__ Alo_p,
    const ushort_t* __restrict__ Wt, const void* bias,
    float* __restrict__ Cf, ushort_t* __restrict__ Chi, ushort_t* __restrict__ Clo,
    int N, int K, int relu, const int* __restrict__ mf)
{
  const int mode = *mf;
  const int split = (mode==1);              // 2-pass only on fp32-input path
  const int rawf32 = (a_kind==0) && (mode==1);
  __shared__ ushort_t Ah[128*AST];
  __shared__ ushort_t Al[128*AST];
  __shared__ ushort_t Bt[128*AST];
  const int tid = threadIdx.x;
  // ---- XCD-bijective chunked swizzle, n-fastest ----
  const int nbx = gridDim.x, nby = gridDim.y;
  const int total = nbx*nby;
  const int f = blockIdx.y*nbx + blockIdx.x;
  const int qq = total>>3, rr = total&7;
  const int xcd = f&7, pos = f>>3;
  const int wg = (xcd<rr ? xcd*(qq+1) : rr*(qq+1) + (xcd-rr)*qq) + pos;
  const int gm0 = (wg / nby)*128, gn0 = (wg % nby)*128;

  const int wv = tid>>6, lane = tid&63;
  const int mh = (wv&1)*64, nh = (wv>>1)*64;
  const int r16 = lane&15, q8 = (lane>>4)*8;
  const int srow = tid>>1, sseg = (tid&1)*16;
  const int sbase = srow*AST + sseg;
  const ushort_t* Ahi_p = (const ushort_t*)A + a_off;   // valid unless rawf32
  v4f acc[4][4];
  #pragma unroll
  for (int i=0;i<4;i++)
    #pragma unroll
    for (int j=0;j<4;j++) acc[i][j] = (v4f){0.f,0.f,0.f,0.f};

  for (int k0=0; k0<K; k0+=32){
    if (k0) __syncthreads();
    {
      const ushort_t* src = Wt + (size_t)(gn0+srow)*K + k0 + sseg;
      ((uint4*)&Bt[sbase])[0]   = ((const uint4*)src)[0];
      ((uint4*)&Bt[sbase+8])[0] = ((const uint4*)src)[1];
    }
    if (!rawf32){
      const ushort_t* src = Ahi_p + (size_t)(gm0+srow)*K + k0 + sseg;
      ((uint4*)&Ah[sbase])[0]   = ((const uint4*)src)[0];
      ((uint4*)&Ah[sbase+8])[0] = ((const uint4*)src)[1];
      if (split){
        const ushort_t* srl = Alo_p + (size_t)(gm0+srow)*K + k0 + sseg;
        ((uint4*)&Al[sbase])[0]   = ((const uint4*)srl)[0];
        ((uint4*)&Al[sbase+8])[0] = ((const uint4*)srl)[1];
      }
    } else {
      const float* src = (const float*)A + a_off + (size_t)(gm0+srow)*K + k0 + sseg;
      #pragma unroll
      for (int v=0;v<4;v++){
        float4 fq = ((const float4*)src)[v];
        float xs[4] = {fq.x, fq.y, fq.z, fq.w};
        #pragma unroll
        for (int e=0;e<4;e++){
          const int idx = sbase + v*4 + e;
          const ushort_t h = f2bfbits(xs[e]);
          Ah[idx] = h;
          Al[idx] = f2bfbits(xs[e] - bf2f(h));
        }
      }
    }
    __syncthreads();
    v8s af[4], bfr[4], al[4];
    #pragma unroll
    for (int mt=0;mt<4;mt++){
      af[mt] = *(const v8s*)&Ah[(mh + mt*16 + r16)*AST + q8];
      if (split) al[mt] = *(const v8s*)&Al[(mh + mt*16 + r16)*AST + q8];
    }
    #pragma unroll
    for (int nt=0;nt<4;nt++)
      bfr[nt] = *(const v8s*)&Bt[(nh + nt*16 + r16)*AST + q8];
    #pragma unroll
    for (int mt=0;mt<4;mt++){
      #pragma unroll
      for (int nt=0;nt<4;nt++){
        acc[mt][nt] = __builtin_amdgcn_mfma_f32_16x16x32_bf16(af[mt], bfr[nt], acc[mt][nt], 0, 0, 0);
        if (split)
          acc[mt][nt] = __builtin_amdgcn_mfma_f32_16x16x32_bf16(al[mt], bfr[nt], acc[mt][nt], 0, 0, 0);
      }
    }
  }
  const int rq = (lane>>4)*4;
  float bv[4];
  #pragma unroll
  for (int nt=0;nt<4;nt++) bv[nt] = ldin(bias, gn0 + nh + nt*16 + r16, mode);
  const int outf = (Cf != nullptr);
  #pragma unroll
  for (int mt=0;mt<4;mt++){
    #pragma unroll
    for (int r=0;r<4;r++){
      const size_t ro = (size_t)(gm0 + mh + mt*16 + rq + r)*N + gn0 + nh + r16;
      #pragma unroll
      for (int nt=0;nt<4;nt++){
        float v = acc[mt][nt][r] + bv[nt];
        if (relu) v = fmaxf(v, 0.f);
        if (outf) Cf[ro + nt*16] = v;
        else {
          const ushort_t hb = f2bfbits(v);
          Chi[ro + nt*16] = hb;
          if (mode==1) Clo[ro + nt*16] = f2bfbits(v - bf2f(hb));
        }
      }
    }
  }
}

// ---------------------------------------------------------------------------
// KV split/transpose prep (unchanged — K/V keep hi/lo, cheap correction)
// ---------------------------------------------------------------------------
__global__ __launch_bounds__(256) void k_kvsplit(
    const float* __restrict__ kws, const float* __restrict__ vws,
    ushort_t* __restrict__ khi, ushort_t* __restrict__ klo,
    ushort_t* __restrict__ vthi, ushort_t* __restrict__ vtlo)
{
  const int row = blockIdx.x;        // 0..255 = b*32 + key
  const int b = row >> 5, key = row & 31;
  const int t = threadIdx.x;         // dim 0..255
  const float f = kws[(size_t)row*256 + t];
  const ushort_t fh = f2bfbits(f);
  khi[(size_t)row*256 + t] = fh;
  klo[(size_t)row*256 + t] = f2bfbits(f - bf2f(fh));
  const float g = vws[(size_t)row*256 + t];
  const ushort_t gh = f2bfbits(g);
  const size_t vt = ((size_t)b*256 + t)*32 + key;
  vthi[vt] = gh;
  vtlo[vt] = f2bfbits(g - bf2f(gh));
}

// ---------------------------------------------------------------------------
// A2: MFMA MHA. Q comes in as bf16 pair (lo only valid/used in mode1).
// K lo and V lo corrections always applied (from fp32 text-side K/V).
// ao out: hi always, lo only in mode1.
// ---------------------------------------------------------------------------
__global__ __launch_bounds__(256) void k_attn2(
    const ushort_t* __restrict__ qcH, const ushort_t* __restrict__ qcL,
    ushort_t* __restrict__ aoh, ushort_t* __restrict__ aol,
    const ushort_t* __restrict__ khi, const ushort_t* __restrict__ klo,
    const ushort_t* __restrict__ vthi, const ushort_t* __restrict__ vtlo,
    const char* __restrict__ tmask, int r0, const int* __restrict__ mf)
{
  const int mode1 = (*mf == 1);
  __shared__ float P[4][16][36];
  const int tid = threadIdx.x;
  const int wv = tid>>6, lane = tid&63;
  const int lrow0 = blockIdx.x*64 + wv*16;        // local row base (chunk-rel)
  const int b = (r0 + lrow0)/NVTOK;               // uniform per wave
  const int m16 = lane&15;
  const int kq = lane>>4;
  const int q8 = kq*8;
  const int key0 = m16, key1 = m16+16;
  const bool msk0 = tmask[b*LT + key0] != 0;
  const bool msk1 = tmask[b*LT + key1] != 0;
  const float scale = 0.17677669529663687f;

  for (int h=0; h<8; ++h){
    const size_t qoff = (size_t)(lrow0 + m16)*256 + h*32 + q8;
    const v8s qh = *(const v8s*)&qcH[qoff];
    v8s ql;
    if (mode1) ql = *(const v8s*)&qcL[qoff];
    const size_t kb0 = ((size_t)(b*32+key0)*256) + h*32 + q8;
    const size_t kb1 = ((size_t)(b*32+key1)*256) + h*32 + q8;
    const v8s kh0 = *(const v8s*)&khi[kb0];
    const v8s kl0 = *(const v8s*)&klo[kb0];
    const v8s kh1 = *(const v8s*)&khi[kb1];
    const v8s kl1 = *(const v8s*)&klo[kb1];
    v4f s0 = (v4f){0.f,0.f,0.f,0.f}, s1 = (v4f){0.f,0.f,0.f,0.f};
    s0 = __builtin_amdgcn_mfma_f32_16x16x32_bf16(qh, kh0, s0, 0,0,0);
    s0 = __builtin_amdgcn_mfma_f32_16x16x32_bf16(qh, kl0, s0, 0,0,0);
    s1 = __builtin_amdgcn_mfma_f32_16x16x32_bf16(qh, kh1, s1, 0,0,0);
    s1 = __builtin_amdgcn_mfma_f32_16x16x32_bf16(qh, kl1, s1, 0,0,0);
    if (mode1){
      s0 = __builtin_amdgcn_mfma_f32_16x16x32_bf16(ql, kh0, s0, 0,0,0);
      s1 = __builtin_amdgcn_mfma_f32_16x16x32_bf16(ql, kh1, s1, 0,0,0);
    }
    float e0[4], e1[4], inv[4];
    #pragma unroll
    for (int r=0;r<4;r++){
      const float a0 = msk0 ? -1e9f : s0[r]*scale;
      const float a1 = msk1 ? -1e9f : s1[r]*scale;
      float mx = fmaxf(a0,a1);
      #pragma unroll
      for (int o=1;o<16;o<<=1) mx = fmaxf(mx, __shfl_xor(mx,o));
      const float x0 = __expf(a0-mx), x1 = __expf(a1-mx);
      float dn = x0+x1;
      #pragma unroll
      for (int o=1;o<16;o<<=1) dn += __shfl_xor(dn,o);
      e0[r]=x0; e1[r]=x1; inv[r] = 1.f/dn;
    }
    #pragma unroll
    for (int r=0;r<4;r++){
      P[wv][kq*4+r][key0] = e0[r];
      P[wv][kq*4+r][key1] = e1[r];
    }
    __syncthreads();
    float pv[8];
    *(float4*)&pv[0] = *(const float4*)&P[wv][m16][q8];
    *(float4*)&pv[4] = *(const float4*)&P[wv][m16][q8+4];
    v8s ph, pl;
    #pragma unroll
    for (int j=0;j<8;j++){
      const ushort_t hb = f2bfbits(pv[j]);
      ph[j] = (short)hb;
      if (mode1) pl[j] = (short)f2bfbits(pv[j] - bf2f(hb));
    }
    const size_t vb0 = ((size_t)(b*256 + h*32 + m16)*32) + q8;
    const size_t vb1 = ((size_t)(b*256 + h*32 + 16 + m16)*32) + q8;
    const v8s vh0 = *(const v8s*)&vthi[vb0];
    const v8s vl0 = *(const v8s*)&vtlo[vb0];
    const v8s vh1 = *(const v8s*)&vthi[vb1];
    const v8s vl1 = *(const v8s*)&vtlo[vb1];
    v4f o0 = (v4f){0.f,0.f,0.f,0.f}, o1 = (v4f){0.f,0.f,0.f,0.f};
    o0 = __builtin_amdgcn_mfma_f32_16x16x32_bf16(ph, vh0, o0, 0,0,0);
    o0 = __builtin_amdgcn_mfma_f32_16x16x32_bf16(ph, vl0, o0, 0,0,0);
    o1 = __builtin_amdgcn_mfma_f32_16x16x32_bf16(ph, vh1, o1, 0,0,0);
    o1 = __builtin_amdgcn_mfma_f32_16x16x32_bf16(ph, vl1, o1, 0,0,0);
    if (mode1){
      o0 = __builtin_amdgcn_mfma_f32_16x16x32_bf16(pl, vh0, o0, 0,0,0);
      o1 = __builtin_amdgcn_mfma_f32_16x16x32_bf16(pl, vh1, o1, 0,0,0);
    }
    __syncthreads();   // protect P before next head overwrites
    #pragma unroll
    for (int r=0;r<4;r++){
      const size_t ro = (size_t)(lrow0 + kq*4 + r)*256 + h*32;
      const float w0 = o0[r]*inv[r], w1 = o1[r]*inv[r];
      const ushort_t h0 = f2bfbits(w0), h1 = f2bfbits(w1);
      aoh[ro + m16]      = h0;
      aoh[ro + 16 + m16] = h1;
      if (mode1){
        aol[ro + m16]      = f2bfbits(w0 - bf2f(h0));
        aol[ro + 16 + m16] = f2bfbits(w1 - bf2f(h1));
      }
    }
  }
}

// ---------------------------------------------------------------------------
// residual + two-pass LayerNorm (text side, unchanged)
// ---------------------------------------------------------------------------
__global__ __launch_bounds__(256) void k_add_ln(
    const float* __restrict__ X, const void* R, size_t r_off, int r_f32,
    void* OUT, size_t o_off, int o_f32,
    void* OUT2, size_t o2_off,
    const void* g, const void* be, const int* __restrict__ mf)
{
  const int mode = *mf;
  const int row = blockIdx.x; const int t = threadIdx.x;
  const size_t idx = (size_t)row*256 + t;
  __shared__ float red[4];
  const float rv = r_f32 ? ((const float*)R)[r_off+idx] : ldin(R, r_off+idx, mode);
  const float v = X[idx] + rv;
  const float m = block_sum(v, red) * (1.f/256.f);
  __syncthreads();
  const float d = v - m;
  const float var = block_sum(d*d, red) * (1.f/256.f);
  const float o = d*rsqrtf(var+1e-5f)*ldin(g,t,mode) + ldin(be,t,mode);
  if (o_f32) ((float*)OUT)[o_off+idx] = o;
  else       stout(OUT, o_off+idx, mode, o);
  if (OUT2)  stout(OUT2, o2_off+idx, mode, o);
}

// ---------------------------------------------------------------------------
// LN1 (vis): v = X + residual(mode-typed) ; out = bf16 hi (+lo in mode1)
// ---------------------------------------------------------------------------
__global__ __launch_bounds__(256) void k_add_ln_pair(
    const float* __restrict__ X, const void* R, size_t r_off,
    ushort_t* __restrict__ OH, ushort_t* __restrict__ OL,
    const void* g, const void* be, const int* __restrict__ mf)
{
  const int mode = *mf;
  const int row = blockIdx.x; const int t = threadIdx.x;
  const size_t idx = (size_t)row*256 + t;
  __shared__ float red[4];
  const float rv = ldin(R, r_off+idx, mode);
  const float v = X[idx] + rv;
  const float m = block_sum(v, red) * (1.f/256.f);
  __syncthreads();
  const float d = v - m;
  const float var = block_sum(d*d, red) * (1.f/256.f);
  const float o = d*rsqrtf(var+1e-5f)*ldin(g,t,mode) + ldin(be,t,mode);
  const ushort_t hb = f2bfbits(o);
  OH[idx] = hb;
  if (mode==1) OL[idx] = f2bfbits(o - bf2f(hb));
}

// ---------------------------------------------------------------------------
// LN2 (vis): v = X + (RH [+RL in mode1]) ; out = mode-typed at offset
// ---------------------------------------------------------------------------
__global__ __launch_bounds__(256) void k_add_ln_pres(
    const float* __restrict__ X,
    const ushort_t* __restrict__ RH, const ushort_t* __restrict__ RL,
    void* OUT, size_t o_off,
    const void* g, const void* be, const int* __restrict__ mf)
{
  const int mode = *mf;
  const int row = blockIdx.x; const int t = threadIdx.x;
  const size_t idx = (size_t)row*256 + t;
  __shared__ float red[4];
  float rv = bf2f(RH[idx]);
  if (mode==1) rv += bf2f(RL[idx]);
  const float v = X[idx] + rv;
  const float m = block_sum(v, red) * (1.f/256.f);
  __syncthreads();
  const float d = v - m;
  const float var = block_sum(d*d, red) * (1.f/256.f);
  const float o = d*rsqrtf(var+1e-5f)*ldin(g,t,mode) + ldin(be,t,mode);
  stout(OUT, o_off+idx, mode, o);
}

// ---------------------------------------------------------------------------
extern "C" void kernel_launch(void* const* d_in, const int* in_sizes, int n_in,
                              void* d_out, int out_size, void* d_ws, size_t ws_size,
                              hipStream_t stream)
{
  (void)n_in; (void)out_size;
  const void* vis_tokens = d_in[0];
  const void* text_tokens= d_in[1];
  const void* vis_value  = d_in[2];
  const void* ref_w = d_in[3];  const void* ref_b = d_in[4];
  const void* off_w = d_in[5];  const void* off_b = d_in[6];
  const void* aw_w  = d_in[7];  const void* aw_b  = d_in[8];
  const void* vproj_w = d_in[9];  const void* vproj_b = d_in[10];
  const void* oproj_w = d_in[11]; const void* oproj_b = d_in[12];
  const void* lvi_out_w = d_in[13]; const void* lvi_out_b = d_in[14];
  const void* lvi_n1_s = d_in[15];  const void* lvi_n1_b = d_in[16];
  const void* lvi_f1_w = d_in[17];  const void* lvi_f1_b = d_in[18];
  const void* lvi_f2_w = d_in[19];  const void* lvi_f2_b = d_in[20];
  const void* lvi_n2_s = d_in[21];  const void* lvi_n2_b = d_in[22];
  const void* mha_qw = d_in[23]; const void* mha_qb = d_in[24];
  const void* mha_kw = d_in[25]; const void* mha_kb = d_in[26];
  const void* mha_vw = d_in[27]; const void* mha_vb = d_in[28];
  const void* mha_ow = d_in[29]; const void* mha_ob = d_in[30];
  const void* vli_out_w = d_in[31]; const void* vli_out_b = d_in[32];
  const void* vli_n1_s = d_in[33];  const void* vli_n1_b = d_in[34];
  const void* vli_f1_w = d_in[35];  const void* vli_f1_b = d_in[36];
  const void* vli_f2_w = d_in[37];  const void* vli_f2_b = d_in[38];
  const void* vli_n2_s = d_in[39];  const void* vli_n2_b = d_in[40];
  const char* tmask = (const char*)d_in[43];
  const char* vmask = (const char*)d_in[44];

  // ---- workspace layout ----
  char* ws = (char*)d_ws;
  int*   flag    = (int*)  (ws + 0);               // 256 B
  float* loc_ws  = (float*)(ws + 256);             // 196608
  float* aw_ws   = (float*)(ws + 196864);          //  98304
  float* ctxt_ws = (float*)(ws + 295168);          // 262144
  float* t_ws    = (float*)(ws + 557312);          // 262144
  float* tout_ws = (float*)(ws + 819456);          // 262144
  float* k_ws    = (float*)(ws + 1081600);         // 262144
  float* v_ws    = (float*)(ws + 1343744);         // 262144
  ushort_t* wtq  = (ushort_t*)(ws + 1605888ull);   // 131072 B
  ushort_t* wto  = (ushort_t*)(ws + 1736960ull);   // 131072 B
  ushort_t* wtf1 = (ushort_t*)(ws + 1868032ull);   // 524288 B
  ushort_t* wtf2 = (ushort_t*)(ws + 2392320ull);   // 524288 B
  ushort_t* wtk   = (ushort_t*)(ws + 2916608ull);  // 131072 B (mha_kw^T)
  ushort_t* wtv   = (ushort_t*)(ws + 3047680ull);  // 131072 B (mha_vw^T)
  ushort_t* wtop  = (ushort_t*)(ws + 3178752ull);  // 131072 B (oproj_w^T)
  ushort_t* wtlo  = (ushort_t*)(ws + 3309824ull);  // 131072 B (lvi_out_w^T)
  ushort_t* wtlf1 = (ushort_t*)(ws + 3440896ull);  // 524288 B (lvi_f1_w^T)
  ushort_t* wtlf2 = (ushort_t*)(ws + 3965184ull);  // 524288 B (lvi_f2_w^T)
  float* hbuf_t   = (float*)(ws + 4489472ull);     // 1048576 B (256x1024)
  float* ybuf     = (float*)(ws + 5538048ull);     // 262144 B
  float* fbuf     = (float*)(ws + 5800192ull);     // 262144 B
  ushort_t* khi   = (ushort_t*)(ws + 6062336ull);  // 131072 B
  ushort_t* klo   = (ushort_t*)(ws + 6193408ull);  // 131072 B
  ushort_t* vthi  = (ushort_t*)(ws + 6324480ull);  // 131072 B
  ushort_t* vtlo  = (ushort_t*)(ws + 6455552ull);  // 131072 B
  const size_t fe = 6586624ull;                    // chunk region start

  // per-row chunk bytes with aliasing (6144 B/row):
  //   region0 (1024 B): qc bf16 pair  <-> ubuf fp32 (qc dead after attn2)
  //   region1 (1024 B): v1 pair
  //   region2 (4096 B): hb pair; first part doubles as ao pair (dead pre-f1)
  long long R_ll = 128;
  if (ws_size > fe) R_ll = (long long)((ws_size - fe) / 6144ull);
  if (R_ll > (long long)MVIS) R_ll = MVIS;
  R_ll &= ~127LL;
  if (R_ll < 128) R_ll = 128;
  const int R = (int)R_ll;
  ushort_t* qcH  = (ushort_t*)(ws + fe);                      // region0
  ushort_t* qcL  = qcH + (size_t)R*256;
  float*    ubuf = (float*)   (ws + fe);                      // alias region0
  ushort_t* v1H  = (ushort_t*)(ws + fe + (size_t)R*1024ull);  // region1
  ushort_t* v1L  = v1H + (size_t)R*256;
  ushort_t* hbH  = (ushort_t*)(ws + fe + (size_t)R*2048ull);  // region2
  ushort_t* hbL  = hbH + (size_t)R*1024;
  ushort_t* aoH  = hbH;                                       // alias (dead pre-f1)
  ushort_t* aoL  = hbH + (size_t)R*256;

  // ---- dtype detect ----
  int ndw = in_sizes[1]/2; if (ndw < 1) ndw = 1;
  k_detect<<<1,256,0,stream>>>((const uint_t*)text_tokens, ndw, flag);

  // ---- weight transposes for MFMA GEMMs ----
  k_transpose<<<dim3(8,8),  256,0,stream>>>(mha_qw,    wtq,   256, 256,  flag);
  k_transpose<<<dim3(8,8),  256,0,stream>>>(mha_ow,    wto,   256, 256,  flag);
  k_transpose<<<dim3(8,32), 256,0,stream>>>(vli_f1_w,  wtf1,  256, 1024, flag);
  k_transpose<<<dim3(32,8), 256,0,stream>>>(vli_f2_w,  wtf2,  1024, 256, flag);
  k_transpose<<<dim3(8,8),  256,0,stream>>>(mha_kw,    wtk,   256, 256,  flag);
  k_transpose<<<dim3(8,8),  256,0,stream>>>(mha_vw,    wtv,   256, 256,  flag);
  k_transpose<<<dim3(8,8),  256,0,stream>>>(oproj_w,   wtop,  256, 256,  flag);
  k_transpose<<<dim3(8,8),  256,0,stream>>>(lvi_out_w, wtlo,  256, 256,  flag);
  k_transpose<<<dim3(8,32), 256,0,stream>>>(lvi_f1_w,  wtlf1, 256, 1024, flag);
  k_transpose<<<dim3(32,8), 256,0,stream>>>(lvi_f2_w,  wtlf2, 1024, 256, flag);

  // ---- text side ----
  k_text_prep<<<MTEXT,256,0,stream>>>(text_tokens, ref_w, ref_b, off_w, off_b,
                                      aw_w, aw_b, loc_ws, aw_ws, flag);
  k_deform<<<MTEXT*NHEAD,64,0,stream>>>(vis_value, vmask, vproj_w, vproj_b,
                                        loc_ws, aw_ws, ctxt_ws, flag);

  // attn-out path: y = ctx@oproj + b ; z = y@lvi_out + b ; t = LN(text + z)
  {
    dim3 g22(2,2);
    k_mgemm<<<g22,256,0,stream>>>(ctxt_ws, 0, 1, wtop, oproj_b, ybuf, 256, 256, 0, flag);
    k_mgemm<<<g22,256,0,stream>>>(ybuf,    0, 1, wtlo, lvi_out_b, fbuf, 256, 256, 0, flag);
    k_add_ln<<<MTEXT,256,0,stream>>>(fbuf, text_tokens, 0, 0,
                                     t_ws, 0, 1, nullptr, 0, lvi_n1_s, lvi_n1_b, flag);
  }
  // ffn path: h = relu(t@f1+b1) ; f = h@f2+b2 ; tout = LN(t + f)
  {
    dim3 g28(2,8), g22(2,2);
    k_mgemm<<<g28,256,0,stream>>>(t_ws,   0, 1, wtlf1, lvi_f1_b, hbuf_t, 1024, 256, 1, flag);
    k_mgemm<<<g22,256,0,stream>>>(hbuf_t, 0, 1, wtlf2, lvi_f2_b, fbuf,   256, 1024, 0, flag);
    k_add_ln<<<MTEXT,256,0,stream>>>(fbuf, t_ws, 0, 1,
                                     tout_ws, 0, 1, d_out, VISSZ, lvi_n2_s, lvi_n2_b, flag);
  }
  // k/v projection of text_out + bf16 hi/lo split (+ V transpose)
  {
    dim3 g22(2,2);
    k_mgemm<<<g22,256,0,stream>>>(tout_ws, 0, 1, wtk, mha_kb, k_ws, 256, 256, 0, flag);
    k_mgemm<<<g22,256,0,stream>>>(tout_ws, 0, 1, wtv, mha_vb, v_ws, 256, 256, 0, flag);
    k_kvsplit<<<256,256,0,stream>>>(k_ws, v_ws, khi, klo, vthi, vtlo);
  }

  // ---- vis side, chunked by R rows ----
  for (int r0 = 0; r0 < MVIS; r0 += R){
    const int nr = (MVIS - r0 < R) ? (MVIS - r0) : R;   // multiple of 128
    dim3 g2(nr/128, 2);
    k_mgemm2<<<g2,256,0,stream>>>(vis_tokens, (size_t)r0*256, 0, nullptr,
                                  wtq, mha_qb, nullptr, qcH, qcL, 256, 256, 0, flag);
    k_attn2<<<nr/64,256,0,stream>>>(qcH, qcL, aoH, aoL, khi, klo, vthi, vtlo,
                                    tmask, r0, flag);
    k_mgemm2<<<g2,256,0,stream>>>(aoH, 0, 2, aoL,
                                  wto, mha_ob, ubuf, nullptr, nullptr, 256, 256, 0, flag);
    k_add_ln_pair<<<nr,256,0,stream>>>(ubuf, vis_tokens, (size_t)r0*256,
                                       v1H, v1L, vli_n1_s, vli_n1_b, flag);
    dim3 g8(nr/128, 8);
    k_mgemm2<<<g8,256,0,stream>>>(v1H, 0, 2, v1L,
                                  wtf1, vli_f1_b, nullptr, hbH, hbL, 1024, 256, 1, flag);
    k_mgemm2<<<g2,256,0,stream>>>(hbH, 0, 2, hbL,
                                  wtf2, vli_f2_b, ubuf, nullptr, nullptr, 256, 1024, 0, flag);
    k_add_ln_pres<<<nr,256,0,stream>>>(ubuf, v1H, v1L,
                                       d_out, (size_t)r0*256, vli_n2_s, vli_n2_b, flag);
  }
}

// Round 6
// 883.561 us; speedup vs baseline: 1.2500x; 1.2500x over previous
//
#include <hip/hip_runtime.h>
#include <hip/hip_bf16.h>
#include <math.h>

typedef __hip_bfloat16 bf16;
typedef unsigned short ushort_t;
typedef unsigned int uint_t;
typedef short v8s __attribute__((ext_vector_type(8)));
typedef float v4f __attribute__((ext_vector_type(4)));

#define NVTOK 9072
#define BATCH 8
#define LT 32
#define DMODEL 256
#define NHEAD 8
#define DHEAD 32
#define MVIS (BATCH*NVTOK)   /* 72576 */
#define MTEXT (BATCH*LT)     /* 256 */
#define VISSZ 18579456ull    /* MVIS*256 elements */

__device__ __forceinline__ float bf2f(ushort_t u){ return __uint_as_float(((uint_t)u)<<16); }
__device__ __forceinline__ ushort_t f2bfbits(float f){
  __hip_bfloat16 h = __float2bfloat16(f);
  union { __hip_bfloat16 h; ushort_t u; } c; c.h = h; return c.u;
}
// mode: 0 = buffers hold bf16, 1 = buffers hold fp32
__device__ __forceinline__ float ldin(const void* p, size_t i, int mode){
  return mode ? ((const float*)p)[i] : bf2f(((const ushort_t*)p)[i]);
}
__device__ __forceinline__ void stout(void* p, size_t i, int mode, float v){
  if (mode) ((float*)p)[i] = v; else ((ushort_t*)p)[i] = f2bfbits(v);
}

// async global->LDS, 16 B per lane. LDS dest must be wave-uniform base +
// lane*16 (m104); our addressing satisfies this (lds byte off = tid*16 + C).
__device__ __forceinline__ void gload_lds16(const void* g, void* l){
  __builtin_amdgcn_global_load_lds(
      (const __attribute__((address_space(1))) unsigned int*)g,
      (__attribute__((address_space(3))) unsigned int*)l, 16, 0, 0);
}

// ---------------------------------------------------------------------------
// D0: dtype detector (unchanged)
// ---------------------------------------------------------------------------
__global__ void k_detect(const uint_t* __restrict__ buf, int n_avail, int* __restrict__ flag){
  __shared__ int zc, bc;
  if (threadIdx.x==0){ zc=0; bc=0; }
  __syncthreads();
  int stride = n_avail/2048; if (stride < 1) stride = 1;
  int nz=0, nb=0;
  for (int i=threadIdx.x; i<2048; i+=256){
    long long idx = (long long)i*stride;
    if (idx >= n_avail) break;
    uint_t d = buf[idx];
    uint_t lo = d & 0xFFFFu;
    int e = (int)((lo >> 7) & 0xFF);
    if (lo == 0) nz++;
    else if (e >= 90 && e <= 160) nb++;
  }
  atomicAdd(&zc, nz); atomicAdd(&bc, nb);
  __syncthreads();
  if (threadIdx.x==0){
    int mode;
    if (zc > 1024) mode = 1;
    else if (bc > 1228) mode = 0;
    else mode = 1;
    *flag = mode;
  }
}

// ---------------------------------------------------------------------------
// W-transpose (unchanged)
// ---------------------------------------------------------------------------
__global__ __launch_bounds__(256) void k_transpose(
    const void* W, ushort_t* __restrict__ Wt, int K, int N,
    const int* __restrict__ mf)
{
  const int mode = *mf;
  __shared__ float tile[32][33];
  const int k0 = blockIdx.x*32, n0 = blockIdx.y*32;
  const int c = threadIdx.x & 31, r8 = threadIdx.x >> 5;
  #pragma unroll
  for (int i=0;i<4;i++){
    const int kk = r8 + i*8;
    tile[kk][c] = ldin(W, (size_t)(k0+kk)*N + n0 + c, mode);
  }
  __syncthreads();
  #pragma unroll
  for (int i=0;i<4;i++){
    const int nn = r8 + i*8;
    Wt[(size_t)(n0+nn)*K + k0 + c] = f2bfbits(tile[c][nn]);
  }
}

// ---------------------------------------------------------------------------
// T1: text prep (unchanged)
// ---------------------------------------------------------------------------
__global__ __launch_bounds__(256) void k_text_prep(
    const void* text,
    const void* ref_w, const void* ref_b,
    const void* off_w, const void* off_b,
    const void* aw_w,  const void* aw_b,
    float* __restrict__ loc_out, float* __restrict__ aw_out,
    const int* __restrict__ mf)
{
  const int mode = *mf;
  const int r = blockIdx.x;
  const int t = threadIdx.x;
  __shared__ float x[256];
  __shared__ float refv[6];
  __shared__ float offv[192];
  __shared__ float logit[96];
  x[t] = ldin(text, (size_t)r*256 + t, mode);
  __syncthreads();
  if (t < 192) {
    float s = 0.f;
    for (int k=0;k<256;k++) s += x[k]*ldin(off_w, (size_t)k*192+t, mode);
    offv[t] = s + ldin(off_b, t, mode);
  } else if (t < 198) {
    int j = t-192;
    float s = 0.f;
    for (int k=0;k<256;k++) s += x[k]*ldin(ref_w, (size_t)k*6+j, mode);
    s += ldin(ref_b, j, mode);
    refv[j] = 1.f/(1.f+expf(-s));
  }
  if (t < 96) {
    float s = 0.f;
    for (int k=0;k<256;k++) s += x[k]*ldin(aw_w, (size_t)k*96+t, mode);
    logit[t] = s + ldin(aw_b, t, mode);
  }
  __syncthreads();
  if (t < 8) {
    float mx = -1e30f;
    for (int j=0;j<12;j++) mx = fmaxf(mx, logit[t*12+j]);
    float e[12]; float den = 0.f;
    for (int j=0;j<12;j++){ e[j] = expf(logit[t*12+j]-mx); den += e[j]; }
    float inv = 1.f/den;
    for (int j=0;j<12;j++) aw_out[(size_t)r*96 + t*12 + j] = e[j]*inv;
  }
  if (t < 192) {
    int rem = t % 24;
    int l = rem >> 3;
    int c = t & 1;
    const float normW[3] = {96.f,48.f,24.f};
    const float normH[3] = {72.f,36.f,18.f};
    float nrm = (c==0) ? normW[l] : normH[l];
    loc_out[(size_t)r*192 + t] = refv[l*2+c] + offv[t]/nrm;
  }
}

// ---------------------------------------------------------------------------
// T2: deformable sampling, lazy vproj (unchanged)
// ---------------------------------------------------------------------------
__global__ __launch_bounds__(64) void k_deform(
    const void* vis_value, const char* __restrict__ vmask,
    const void* vproj_w, const void* vproj_b,
    const float* __restrict__ loc, const float* __restrict__ aw,
    float* __restrict__ ctx_out, const int* __restrict__ mf)
{
  const int mode = *mf;
  const int blk = blockIdx.x;      // r*8 + h
  const int r = blk >> 3;
  const int h = blk & 7;
  const int b = r >> 5;
  const int t = threadIdx.x;
  const int Hs[3] = {72,36,18};
  const int Wsz[3] = {96,48,24};
  const int stl[3] = {0,6912,8640};
  float s0=0.f,s1=0.f,s2=0.f,s3=0.f, wsum=0.f;
  for (int l=0;l<3;l++){
    for (int p=0;p<4;p++){
      const int sIdx = blk*12 + l*4 + p;
      const float a  = aw[sIdx];
      const float X = loc[sIdx*2+0]*(float)Wsz[l] - 0.5f;
      const float Y = loc[sIdx*2+1]*(float)Hs[l] - 0.5f;
      const float x0f = floorf(X), y0f = floorf(Y);
      const int x0 = (int)x0f, y0 = (int)y0f;
      const float wx = X-x0f, wy = Y-y0f;
      const float cw[4] = {(1.f-wx)*(1.f-wy), wx*(1.f-wy), (1.f-wx)*wy, wx*wy};
      const int cx[4] = {x0,x0+1,x0,x0+1};
      const int cy[4] = {y0,y0,y0+1,y0+1};
      for (int c=0;c<4;c++){
        if (cx[c]>=0 && cx[c]<Wsz[l] && cy[c]>=0 && cy[c]<Hs[l]){
          const size_t pos = (size_t)b*NVTOK + stl[l] + cy[c]*Wsz[l] + cx[c];
          if (vmask[pos]) continue;
          const float w = a*cw[c];
          wsum += w;
          const size_t base = pos*256 + t*4;
          s0 += w*ldin(vis_value, base+0, mode);
          s1 += w*ldin(vis_value, base+1, mode);
          s2 += w*ldin(vis_value, base+2, mode);
          s3 += w*ldin(vis_value, base+3, mode);
        }
      }
    }
  }
  __shared__ float sh[256];
  sh[t*4+0]=s0; sh[t*4+1]=s1; sh[t*4+2]=s2; sh[t*4+3]=s3;
  __syncthreads();
  if (t < 32) {
    const int col = h*32 + t;
    float acc = wsum * ldin(vproj_b, col, mode);
    for (int k=0;k<256;k++) acc += sh[k]*ldin(vproj_w, (size_t)k*256+col, mode);
    ctx_out[(size_t)r*256 + col] = acc;
  }
}

__device__ __forceinline__ float block_sum(float v, float* red){
  float sm = v;
  #pragma unroll
  for (int o=32;o>0;o>>=1) sm += __shfl_down(sm,o);
  const int t = threadIdx.x;
  __syncthreads();
  if ((t&63)==0) red[t>>6] = sm;
  __syncthreads();
  return red[0]+red[1]+red[2]+red[3];
}

// ---------------------------------------------------------------------------
// MFMA GEMM (text side, unchanged — tiny M, full hi/lo precision)
// ---------------------------------------------------------------------------
__global__ __launch_bounds__(256) void k_mgemm(
    const void* A, size_t a_off, int a_kind,
    const ushort_t* __restrict__ Wt, const void* bias, float* __restrict__ C,
    int N, int K, int relu, const int* __restrict__ mf)
{
  const int mode = *mf;
  const int split = (a_kind==1) || (mode==1);
  __shared__ ushort_t Ah[128*32];
  __shared__ ushort_t Al[128*32];
  __shared__ ushort_t Bt[128*32];
  const int tid = threadIdx.x;
  const int gm0 = blockIdx.x*128, gn0 = blockIdx.y*128;
  const int wv = tid>>6, lane = tid&63;
  const int mh = (wv&1)*64, nh = (wv>>1)*64;
  const int r16 = lane&15, q8 = (lane>>4)*8;
  const int srow = tid>>1, sseg = (tid&1)*16;
  v4f acc[4][4];
  #pragma unroll
  for (int i=0;i<4;i++)
    #pragma unroll
    for (int j=0;j<4;j++) acc[i][j] = (v4f){0.f,0.f,0.f,0.f};

  for (int k0=0; k0<K; k0+=32){
    if (k0) __syncthreads();
    {
      const ushort_t* src = Wt + (size_t)(gn0+srow)*K + k0 + sseg;
      ((uint4*)&Bt[srow*32+sseg])[0]   = ((const uint4*)src)[0];
      ((uint4*)&Bt[srow*32+sseg+8])[0] = ((const uint4*)src)[1];
    }
    if (!split){
      const ushort_t* src = (const ushort_t*)A + a_off + (size_t)(gm0+srow)*K + k0 + sseg;
      ((uint4*)&Ah[srow*32+sseg])[0]   = ((const uint4*)src)[0];
      ((uint4*)&Ah[srow*32+sseg+8])[0] = ((const uint4*)src)[1];
    } else {
      const float* src = (const float*)A + a_off + (size_t)(gm0+srow)*K + k0 + sseg;
      #pragma unroll
      for (int v=0;v<4;v++){
        float4 f = ((const float4*)src)[v];
        float xs[4] = {f.x, f.y, f.z, f.w};
        #pragma unroll
        for (int e=0;e<4;e++){
          const int idx = srow*32 + sseg + v*4 + e;
          const ushort_t h = f2bfbits(xs[e]);
          Ah[idx] = h;
          Al[idx] = f2bfbits(xs[e] - bf2f(h));
        }
      }
    }
    __syncthreads();
    v8s af[4], bfr[4], al[4];
    #pragma unroll
    for (int mt=0;mt<4;mt++){
      af[mt] = *(const v8s*)&Ah[(mh + mt*16 + r16)*32 + q8];
      if (split) al[mt] = *(const v8s*)&Al[(mh + mt*16 + r16)*32 + q8];
    }
    #pragma unroll
    for (int nt=0;nt<4;nt++)
      bfr[nt] = *(const v8s*)&Bt[(nh + nt*16 + r16)*32 + q8];
    #pragma unroll
    for (int mt=0;mt<4;mt++){
      #pragma unroll
      for (int nt=0;nt<4;nt++){
        acc[mt][nt] = __builtin_amdgcn_mfma_f32_16x16x32_bf16(af[mt], bfr[nt], acc[mt][nt], 0, 0, 0);
        if (split)
          acc[mt][nt] = __builtin_amdgcn_mfma_f32_16x16x32_bf16(al[mt], bfr[nt], acc[mt][nt], 0, 0, 0);
      }
    }
  }
  const int rq = (lane>>4)*4;
  float bv[4];
  #pragma unroll
  for (int nt=0;nt<4;nt++) bv[nt] = ldin(bias, gn0 + nh + nt*16 + r16, mode);
  #pragma unroll
  for (int mt=0;mt<4;mt++){
    #pragma unroll
    for (int r=0;r<4;r++){
      const size_t ro = (size_t)(gm0 + mh + mt*16 + rq + r)*N + gn0 + nh + r16;
      #pragma unroll
      for (int nt=0;nt<4;nt++){
        float v = acc[mt][nt][r] + bv[nt];
        if (relu) v = fmaxf(v, 0.f);
        C[ro + nt*16] = v;
      }
    }
  }
}

// ---------------------------------------------------------------------------
// V3 MFMA GEMM (vis side): single-pass bf16 activations (both modes).
//   a_kind=0: raw input. mode0 -> bf16, gload_lds direct; mode1 -> fp32,
//             reg-staged hi-only conversion.
//   a_kind=2: bf16 activation buffer -> gload_lds direct.
// Staging via __builtin_amdgcn_global_load_lds width=16 (m97 ladder step):
// LDS linear [128][32] ushort, lds byte off = tid*16 (+4096 for 2nd issue),
// lane-linear within each wave (m104 constraint satisfied).
// XCD-bijective chunked block swizzle, n-fastest. Output fp32 or bf16-hi.
// ---------------------------------------------------------------------------
__global__ __launch_bounds__(256) void k_mgemm3(
    const void* A, size_t a_off, int a_kind,
    const ushort_t* __restrict__ Wt, const void* bias,
    float* __restrict__ Cf, ushort_t* __restrict__ Chi,
    int N, int K, int relu, const int* __restrict__ mf)
{
  const int mode = *mf;
  const int rawf32 = (a_kind==0) && (mode==1);
  __shared__ ushort_t Ah[128*32];
  __shared__ ushort_t Bt[128*32];
  const int tid = threadIdx.x;
  // ---- XCD-bijective chunked swizzle, n-fastest ----
  const int nbx = gridDim.x, nby = gridDim.y;
  const int total = nbx*nby;
  const int f = blockIdx.y*nbx + blockIdx.x;
  const int qq = total>>3, rr = total&7;
  const int xcd = f&7, pos = f>>3;
  const int wg = (xcd<rr ? xcd*(qq+1) : rr*(qq+1) + (xcd-rr)*qq) + pos;
  const int gm0 = (wg / nby)*128, gn0 = (wg % nby)*128;

  const int wv = tid>>6, lane = tid&63;
  const int mh = (wv&1)*64, nh = (wv>>1)*64;
  const int r16 = lane&15, q8 = (lane>>4)*8;
  // gload_lds addressing: row = tid>>2 (+64), col = (tid&3)*8 ushorts
  const int grow = tid>>2;
  const int gcol = (tid&3)*8;
  // rawf32 reg-staging addressing
  const int srow = tid>>1, sseg = (tid&1)*16;
  const ushort_t* Abf = (const ushort_t*)A + a_off;
  v4f acc[4][4];
  #pragma unroll
  for (int i=0;i<4;i++)
    #pragma unroll
    for (int j=0;j<4;j++) acc[i][j] = (v4f){0.f,0.f,0.f,0.f};

  for (int k0=0; k0<K; k0+=32){
    if (k0) __syncthreads();
    gload_lds16(Wt + (size_t)(gn0+grow)*K    + k0 + gcol, &Bt[grow*32      + gcol]);
    gload_lds16(Wt + (size_t)(gn0+grow+64)*K + k0 + gcol, &Bt[(grow+64)*32 + gcol]);
    if (!rawf32){
      gload_lds16(Abf + (size_t)(gm0+grow)*K    + k0 + gcol, &Ah[grow*32      + gcol]);
      gload_lds16(Abf + (size_t)(gm0+grow+64)*K + k0 + gcol, &Ah[(grow+64)*32 + gcol]);
    } else {
      const float* src = (const float*)A + a_off + (size_t)(gm0+srow)*K + k0 + sseg;
      #pragma unroll
      for (int v=0;v<4;v++){
        float4 fq = ((const float4*)src)[v];
        float xs[4] = {fq.x, fq.y, fq.z, fq.w};
        #pragma unroll
        for (int e=0;e<4;e++)
          Ah[srow*32 + sseg + v*4 + e] = f2bfbits(xs[e]);
      }
    }
    __syncthreads();
    v8s af[4], bfr[4];
    #pragma unroll
    for (int mt=0;mt<4;mt++)
      af[mt] = *(const v8s*)&Ah[(mh + mt*16 + r16)*32 + q8];
    #pragma unroll
    for (int nt=0;nt<4;nt++)
      bfr[nt] = *(const v8s*)&Bt[(nh + nt*16 + r16)*32 + q8];
    #pragma unroll
    for (int mt=0;mt<4;mt++){
      #pragma unroll
      for (int nt=0;nt<4;nt++)
        acc[mt][nt] = __builtin_amdgcn_mfma_f32_16x16x32_bf16(af[mt], bfr[nt], acc[mt][nt], 0, 0, 0);
    }
  }
  const int rq = (lane>>4)*4;
  float bv[4];
  #pragma unroll
  for (int nt=0;nt<4;nt++) bv[nt] = ldin(bias, gn0 + nh + nt*16 + r16, mode);
  const int outf = (Cf != nullptr);
  #pragma unroll
  for (int mt=0;mt<4;mt++){
    #pragma unroll
    for (int r=0;r<4;r++){
      const size_t ro = (size_t)(gm0 + mh + mt*16 + rq + r)*N + gn0 + nh + r16;
      #pragma unroll
      for (int nt=0;nt<4;nt++){
        float v = acc[mt][nt][r] + bv[nt];
        if (relu) v = fmaxf(v, 0.f);
        if (outf) Cf[ro + nt*16] = v;
        else      Chi[ro + nt*16] = f2bfbits(v);
      }
    }
  }
}

// ---------------------------------------------------------------------------
// KV split/transpose prep (unchanged — K/V keep hi/lo, cheap correction)
// ---------------------------------------------------------------------------
__global__ __launch_bounds__(256) void k_kvsplit(
    const float* __restrict__ kws, const float* __restrict__ vws,
    ushort_t* __restrict__ khi, ushort_t* __restrict__ klo,
    ushort_t* __restrict__ vthi, ushort_t* __restrict__ vtlo)
{
  const int row = blockIdx.x;        // 0..255 = b*32 + key
  const int b = row >> 5, key = row & 31;
  const int t = threadIdx.x;         // dim 0..255
  const float f = kws[(size_t)row*256 + t];
  const ushort_t fh = f2bfbits(f);
  khi[(size_t)row*256 + t] = fh;
  klo[(size_t)row*256 + t] = f2bfbits(f - bf2f(fh));
  const float g = vws[(size_t)row*256 + t];
  const ushort_t gh = f2bfbits(g);
  const size_t vt = ((size_t)b*256 + t)*32 + key;
  vthi[vt] = gh;
  vtlo[vt] = f2bfbits(g - bf2f(gh));
}

// ---------------------------------------------------------------------------
// A2: MFMA MHA. Q bf16-hi; K/V hi+lo corrections kept (text-derived fp32).
// ao out bf16-hi.
// ---------------------------------------------------------------------------
__global__ __launch_bounds__(256) void k_attn2(
    const ushort_t* __restrict__ qcH,
    ushort_t* __restrict__ aoh,
    const ushort_t* __restrict__ khi, const ushort_t* __restrict__ klo,
    const ushort_t* __restrict__ vthi, const ushort_t* __restrict__ vtlo,
    const char* __restrict__ tmask, int r0)
{
  __shared__ float P[4][16][36];
  const int tid = threadIdx.x;
  const int wv = tid>>6, lane = tid&63;
  const int lrow0 = blockIdx.x*64 + wv*16;        // local row base (chunk-rel)
  const int b = (r0 + lrow0)/NVTOK;               // uniform per wave
  const int m16 = lane&15;
  const int kq = lane>>4;
  const int q8 = kq*8;
  const int key0 = m16, key1 = m16+16;
  const bool msk0 = tmask[b*LT + key0] != 0;
  const bool msk1 = tmask[b*LT + key1] != 0;
  const float scale = 0.17677669529663687f;

  for (int h=0; h<8; ++h){
    const size_t qoff = (size_t)(lrow0 + m16)*256 + h*32 + q8;
    const v8s qh = *(const v8s*)&qcH[qoff];
    const size_t kb0 = ((size_t)(b*32+key0)*256) + h*32 + q8;
    const size_t kb1 = ((size_t)(b*32+key1)*256) + h*32 + q8;
    const v8s kh0 = *(const v8s*)&khi[kb0];
    const v8s kl0 = *(const v8s*)&klo[kb0];
    const v8s kh1 = *(const v8s*)&khi[kb1];
    const v8s kl1 = *(const v8s*)&klo[kb1];
    v4f s0 = (v4f){0.f,0.f,0.f,0.f}, s1 = (v4f){0.f,0.f,0.f,0.f};
    s0 = __builtin_amdgcn_mfma_f32_16x16x32_bf16(qh, kh0, s0, 0,0,0);
    s0 = __builtin_amdgcn_mfma_f32_16x16x32_bf16(qh, kl0, s0, 0,0,0);
    s1 = __builtin_amdgcn_mfma_f32_16x16x32_bf16(qh, kh1, s1, 0,0,0);
    s1 = __builtin_amdgcn_mfma_f32_16x16x32_bf16(qh, kl1, s1, 0,0,0);
    float e0[4], e1[4], inv[4];
    #pragma unroll
    for (int r=0;r<4;r++){
      const float a0 = msk0 ? -1e9f : s0[r]*scale;
      const float a1 = msk1 ? -1e9f : s1[r]*scale;
      float mx = fmaxf(a0,a1);
      #pragma unroll
      for (int o=1;o<16;o<<=1) mx = fmaxf(mx, __shfl_xor(mx,o));
      const float x0 = __expf(a0-mx), x1 = __expf(a1-mx);
      float dn = x0+x1;
      #pragma unroll
      for (int o=1;o<16;o<<=1) dn += __shfl_xor(dn,o);
      e0[r]=x0; e1[r]=x1; inv[r] = 1.f/dn;
    }
    #pragma unroll
    for (int r=0;r<4;r++){
      P[wv][kq*4+r][key0] = e0[r];
      P[wv][kq*4+r][key1] = e1[r];
    }
    __syncthreads();
    float pv[8];
    *(float4*)&pv[0] = *(const float4*)&P[wv][m16][q8];
    *(float4*)&pv[4] = *(const float4*)&P[wv][m16][q8+4];
    v8s ph;
    #pragma unroll
    for (int j=0;j<8;j++) ph[j] = (short)f2bfbits(pv[j]);
    const size_t vb0 = ((size_t)(b*256 + h*32 + m16)*32) + q8;
    const size_t vb1 = ((size_t)(b*256 + h*32 + 16 + m16)*32) + q8;
    const v8s vh0 = *(const v8s*)&vthi[vb0];
    const v8s vl0 = *(const v8s*)&vtlo[vb0];
    const v8s vh1 = *(const v8s*)&vthi[vb1];
    const v8s vl1 = *(const v8s*)&vtlo[vb1];
    v4f o0 = (v4f){0.f,0.f,0.f,0.f}, o1 = (v4f){0.f,0.f,0.f,0.f};
    o0 = __builtin_amdgcn_mfma_f32_16x16x32_bf16(ph, vh0, o0, 0,0,0);
    o0 = __builtin_amdgcn_mfma_f32_16x16x32_bf16(ph, vl0, o0, 0,0,0);
    o1 = __builtin_amdgcn_mfma_f32_16x16x32_bf16(ph, vh1, o1, 0,0,0);
    o1 = __builtin_amdgcn_mfma_f32_16x16x32_bf16(ph, vl1, o1, 0,0,0);
    __syncthreads();   // protect P before next head overwrites
    #pragma unroll
    for (int r=0;r<4;r++){
      const size_t ro = (size_t)(lrow0 + kq*4 + r)*256 + h*32;
      aoh[ro + m16]      = f2bfbits(o0[r]*inv[r]);
      aoh[ro + 16 + m16] = f2bfbits(o1[r]*inv[r]);
    }
  }
}

// ---------------------------------------------------------------------------
// residual + two-pass LayerNorm (text side, unchanged)
// ---------------------------------------------------------------------------
__global__ __launch_bounds__(256) void k_add_ln(
    const float* __restrict__ X, const void* R, size_t r_off, int r_f32,
    void* OUT, size_t o_off, int o_f32,
    void* OUT2, size_t o2_off,
    const void* g, const void* be, const int* __restrict__ mf)
{
  const int mode = *mf;
  const int row = blockIdx.x; const int t = threadIdx.x;
  const size_t idx = (size_t)row*256 + t;
  __shared__ float red[4];
  const float rv = r_f32 ? ((const float*)R)[r_off+idx] : ldin(R, r_off+idx, mode);
  const float v = X[idx] + rv;
  const float m = block_sum(v, red) * (1.f/256.f);
  __syncthreads();
  const float d = v - m;
  const float var = block_sum(d*d, red) * (1.f/256.f);
  const float o = d*rsqrtf(var+1e-5f)*ldin(g,t,mode) + ldin(be,t,mode);
  if (o_f32) ((float*)OUT)[o_off+idx] = o;
  else       stout(OUT, o_off+idx, mode, o);
  if (OUT2)  stout(OUT2, o2_off+idx, mode, o);
}

// ---------------------------------------------------------------------------
// LN1 (vis): v = X + residual(mode-typed) ; out = bf16 hi
// ---------------------------------------------------------------------------
__global__ __launch_bounds__(256) void k_add_ln_h(
    const float* __restrict__ X, const void* R, size_t r_off,
    ushort_t* __restrict__ OH,
    const void* g, const void* be, const int* __restrict__ mf)
{
  const int mode = *mf;
  const int row = blockIdx.x; const int t = threadIdx.x;
  const size_t idx = (size_t)row*256 + t;
  __shared__ float red[4];
  const float rv = ldin(R, r_off+idx, mode);
  const float v = X[idx] + rv;
  const float m = block_sum(v, red) * (1.f/256.f);
  __syncthreads();
  const float d = v - m;
  const float var = block_sum(d*d, red) * (1.f/256.f);
  const float o = d*rsqrtf(var+1e-5f)*ldin(g,t,mode) + ldin(be,t,mode);
  OH[idx] = f2bfbits(o);
}

// ---------------------------------------------------------------------------
// LN2 (vis): v = X + RH ; out = mode-typed at offset
// ---------------------------------------------------------------------------
__global__ __launch_bounds__(256) void k_add_ln_pres(
    const float* __restrict__ X,
    const ushort_t* __restrict__ RH,
    void* OUT, size_t o_off,
    const void* g, const void* be, const int* __restrict__ mf)
{
  const int mode = *mf;
  const int row = blockIdx.x; const int t = threadIdx.x;
  const size_t idx = (size_t)row*256 + t;
  __shared__ float red[4];
  const float rv = bf2f(RH[idx]);
  const float v = X[idx] + rv;
  const float m = block_sum(v, red) * (1.f/256.f);
  __syncthreads();
  const float d = v - m;
  const float var = block_sum(d*d, red) * (1.f/256.f);
  const float o = d*rsqrtf(var+1e-5f)*ldin(g,t,mode) + ldin(be,t,mode);
  stout(OUT, o_off+idx, mode, o);
}

// ---------------------------------------------------------------------------
extern "C" void kernel_launch(void* const* d_in, const int* in_sizes, int n_in,
                              void* d_out, int out_size, void* d_ws, size_t ws_size,
                              hipStream_t stream)
{
  (void)n_in; (void)out_size;
  const void* vis_tokens = d_in[0];
  const void* text_tokens= d_in[1];
  const void* vis_value  = d_in[2];
  const void* ref_w = d_in[3];  const void* ref_b = d_in[4];
  const void* off_w = d_in[5];  const void* off_b = d_in[6];
  const void* aw_w  = d_in[7];  const void* aw_b  = d_in[8];
  const void* vproj_w = d_in[9];  const void* vproj_b = d_in[10];
  const void* oproj_w = d_in[11]; const void* oproj_b = d_in[12];
  const void* lvi_out_w = d_in[13]; const void* lvi_out_b = d_in[14];
  const void* lvi_n1_s = d_in[15];  const void* lvi_n1_b = d_in[16];
  const void* lvi_f1_w = d_in[17];  const void* lvi_f1_b = d_in[18];
  const void* lvi_f2_w = d_in[19];  const void* lvi_f2_b = d_in[20];
  const void* lvi_n2_s = d_in[21];  const void* lvi_n2_b = d_in[22];
  const void* mha_qw = d_in[23]; const void* mha_qb = d_in[24];
  const void* mha_kw = d_in[25]; const void* mha_kb = d_in[26];
  const void* mha_vw = d_in[27]; const void* mha_vb = d_in[28];
  const void* mha_ow = d_in[29]; const void* mha_ob = d_in[30];
  const void* vli_out_w = d_in[31]; const void* vli_out_b = d_in[32];
  const void* vli_n1_s = d_in[33];  const void* vli_n1_b = d_in[34];
  const void* vli_f1_w = d_in[35];  const void* vli_f1_b = d_in[36];
  const void* vli_f2_w = d_in[37];  const void* vli_f2_b = d_in[38];
  const void* vli_n2_s = d_in[39];  const void* vli_n2_b = d_in[40];
  const char* tmask = (const char*)d_in[43];
  const char* vmask = (const char*)d_in[44];

  // ---- workspace layout ----
  char* ws = (char*)d_ws;
  int*   flag    = (int*)  (ws + 0);               // 256 B
  float* loc_ws  = (float*)(ws + 256);             // 196608
  float* aw_ws   = (float*)(ws + 196864);          //  98304
  float* ctxt_ws = (float*)(ws + 295168);          // 262144
  float* t_ws    = (float*)(ws + 557312);          // 262144
  float* tout_ws = (float*)(ws + 819456);          // 262144
  float* k_ws    = (float*)(ws + 1081600);         // 262144
  float* v_ws    = (float*)(ws + 1343744);         // 262144
  ushort_t* wtq  = (ushort_t*)(ws + 1605888ull);   // 131072 B
  ushort_t* wto  = (ushort_t*)(ws + 1736960ull);   // 131072 B
  ushort_t* wtf1 = (ushort_t*)(ws + 1868032ull);   // 524288 B
  ushort_t* wtf2 = (ushort_t*)(ws + 2392320ull);   // 524288 B
  ushort_t* wtk   = (ushort_t*)(ws + 2916608ull);  // 131072 B (mha_kw^T)
  ushort_t* wtv   = (ushort_t*)(ws + 3047680ull);  // 131072 B (mha_vw^T)
  ushort_t* wtop  = (ushort_t*)(ws + 3178752ull);  // 131072 B (oproj_w^T)
  ushort_t* wtlo  = (ushort_t*)(ws + 3309824ull);  // 131072 B (lvi_out_w^T)
  ushort_t* wtlf1 = (ushort_t*)(ws + 3440896ull);  // 524288 B (lvi_f1_w^T)
  ushort_t* wtlf2 = (ushort_t*)(ws + 3965184ull);  // 524288 B (lvi_f2_w^T)
  float* hbuf_t   = (float*)(ws + 4489472ull);     // 1048576 B (256x1024)
  float* ybuf     = (float*)(ws + 5538048ull);     // 262144 B
  float* fbuf     = (float*)(ws + 5800192ull);     // 262144 B
  ushort_t* khi   = (ushort_t*)(ws + 6062336ull);  // 131072 B
  ushort_t* klo   = (ushort_t*)(ws + 6193408ull);  // 131072 B
  ushort_t* vthi  = (ushort_t*)(ws + 6324480ull);  // 131072 B
  ushort_t* vtlo  = (ushort_t*)(ws + 6455552ull);  // 131072 B
  const size_t fe = 6586624ull;                    // chunk region start

  // per-row chunk bytes (3584 B/row), hi-only activations:
  //   region0 (1024 B): ubuf fp32; first 512 B alias qc bf16 (dead after attn2)
  //   region1 ( 512 B): v1 bf16
  //   region2 (2048 B): hb bf16; first 512 B alias ao bf16 (dead pre-f1)
  long long R_ll = 128;
  if (ws_size > fe) R_ll = (long long)((ws_size - fe) / 3584ull);
  if (R_ll > (long long)MVIS) R_ll = MVIS;
  R_ll &= ~127LL;
  if (R_ll < 128) R_ll = 128;
  const int R = (int)R_ll;
  ushort_t* qcH  = (ushort_t*)(ws + fe);                      // region0 alias
  float*    ubuf = (float*)   (ws + fe);                      // region0
  ushort_t* v1H  = (ushort_t*)(ws + fe + (size_t)R*1024ull);  // region1
  ushort_t* hbH  = (ushort_t*)(ws + fe + (size_t)R*1536ull);  // region2
  ushort_t* aoH  = hbH;                                       // alias (dead pre-f1)

  // ---- dtype detect ----
  int ndw = in_sizes[1]/2; if (ndw < 1) ndw = 1;
  k_detect<<<1,256,0,stream>>>((const uint_t*)text_tokens, ndw, flag);

  // ---- weight transposes for MFMA GEMMs ----
  k_transpose<<<dim3(8,8),  256,0,stream>>>(mha_qw,    wtq,   256, 256,  flag);
  k_transpose<<<dim3(8,8),  256,0,stream>>>(mha_ow,    wto,   256, 256,  flag);
  k_transpose<<<dim3(8,32), 256,0,stream>>>(vli_f1_w,  wtf1,  256, 1024, flag);
  k_transpose<<<dim3(32,8), 256,0,stream>>>(vli_f2_w,  wtf2,  1024, 256, flag);
  k_transpose<<<dim3(8,8),  256,0,stream>>>(mha_kw,    wtk,   256, 256,  flag);
  k_transpose<<<dim3(8,8),  256,0,stream>>>(mha_vw,    wtv,   256, 256,  flag);
  k_transpose<<<dim3(8,8),  256,0,stream>>>(oproj_w,   wtop,  256, 256,  flag);
  k_transpose<<<dim3(8,8),  256,0,stream>>>(lvi_out_w, wtlo,  256, 256,  flag);
  k_transpose<<<dim3(8,32), 256,0,stream>>>(lvi_f1_w,  wtlf1, 256, 1024, flag);
  k_transpose<<<dim3(32,8), 256,0,stream>>>(lvi_f2_w,  wtlf2, 1024, 256, flag);

  // ---- text side ----
  k_text_prep<<<MTEXT,256,0,stream>>>(text_tokens, ref_w, ref_b, off_w, off_b,
                                      aw_w, aw_b, loc_ws, aw_ws, flag);
  k_deform<<<MTEXT*NHEAD,64,0,stream>>>(vis_value, vmask, vproj_w, vproj_b,
                                        loc_ws, aw_ws, ctxt_ws, flag);

  // attn-out path: y = ctx@oproj + b ; z = y@lvi_out + b ; t = LN(text + z)
  {
    dim3 g22(2,2);
    k_mgemm<<<g22,256,0,stream>>>(ctxt_ws, 0, 1, wtop, oproj_b, ybuf, 256, 256, 0, flag);
    k_mgemm<<<g22,256,0,stream>>>(ybuf,    0, 1, wtlo, lvi_out_b, fbuf, 256, 256, 0, flag);
    k_add_ln<<<MTEXT,256,0,stream>>>(fbuf, text_tokens, 0, 0,
                                     t_ws, 0, 1, nullptr, 0, lvi_n1_s, lvi_n1_b, flag);
  }
  // ffn path: h = relu(t@f1+b1) ; f = h@f2+b2 ; tout = LN(t + f)
  {
    dim3 g28(2,8), g22(2,2);
    k_mgemm<<<g28,256,0,stream>>>(t_ws,   0, 1, wtlf1, lvi_f1_b, hbuf_t, 1024, 256, 1, flag);
    k_mgemm<<<g22,256,0,stream>>>(hbuf_t, 0, 1, wtlf2, lvi_f2_b, fbuf,   256, 1024, 0, flag);
    k_add_ln<<<MTEXT,256,0,stream>>>(fbuf, t_ws, 0, 1,
                                     tout_ws, 0, 1, d_out, VISSZ, lvi_n2_s, lvi_n2_b, flag);
  }
  // k/v projection of text_out + bf16 hi/lo split (+ V transpose)
  {
    dim3 g22(2,2);
    k_mgemm<<<g22,256,0,stream>>>(tout_ws, 0, 1, wtk, mha_kb, k_ws, 256, 256, 0, flag);
    k_mgemm<<<g22,256,0,stream>>>(tout_ws, 0, 1, wtv, mha_vb, v_ws, 256, 256, 0, flag);
    k_kvsplit<<<256,256,0,stream>>>(k_ws, v_ws, khi, klo, vthi, vtlo);
  }

  // ---- vis side, chunked by R rows ----
  for (int r0 = 0; r0 < MVIS; r0 += R){
    const int nr = (MVIS - r0 < R) ? (MVIS - r0) : R;   // multiple of 128
    dim3 g2(nr/128, 2);
    k_mgemm3<<<g2,256,0,stream>>>(vis_tokens, (size_t)r0*256, 0,
                                  wtq, mha_qb, nullptr, qcH, 256, 256, 0, flag);
    k_attn2<<<nr/64,256,0,stream>>>(qcH, aoH, khi, klo, vthi, vtlo, tmask, r0);
    k_mgemm3<<<g2,256,0,stream>>>(aoH, 0, 2,
                                  wto, mha_ob, ubuf, nullptr, 256, 256, 0, flag);
    k_add_ln_h<<<nr,256,0,stream>>>(ubuf, vis_tokens, (size_t)r0*256,
                                    v1H, vli_n1_s, vli_n1_b, flag);
    dim3 g8(nr/128, 8);
    k_mgemm3<<<g8,256,0,stream>>>(v1H, 0, 2,
                                  wtf1, vli_f1_b, nullptr, hbH, 1024, 256, 1, flag);
    k_mgemm3<<<g2,256,0,stream>>>(hbH, 0, 2,
                                  wtf2, vli_f2_b, ubuf, nullptr, 256, 1024, 0, flag);
    k_add_ln_pres<<<nr,256,0,stream>>>(ubuf, v1H,
                                       d_out, (size_t)r0*256, vli_n2_s, vli_n2_b, flag);
  }
}